// Round 1
// baseline (489.958 us; speedup 1.0000x reference)
//
#include <hip/hip_runtime.h>

#define C_   256
#define CR_  64
#define HW_  3136
#define W_   56
#define H_   56
#define G_   16
#define NK_  144   // K*K*G

// reduce_w [64][256] -> wredT [256][64]  (so the hot loop reads consecutive
// wave-uniform floats -> s_load_dwordx16 on the scalar pipe)
__global__ void transpose_rw(const float* __restrict__ rw, float* __restrict__ rwT) {
    int idx = blockIdx.x * 256 + threadIdx.x;   // 16384 total
    int rr = idx >> 8;
    int c  = idx & 255;
    rwT[c * 64 + rr] = rw[idx];
}

__global__ __launch_bounds__(128)
void inv_fused(const float* __restrict__ x,
               const float* __restrict__ wredT,
               const float* __restrict__ span_w,
               const float* __restrict__ span_b,
               float* __restrict__ out) {
    __shared__ float r_lds[2][64][64];   // [half][rr][pixel] -- stride-1 in lane => conflict-free

    const int b    = blockIdx.x / 49;    // 49 pixel-tiles per batch image
    const int tile = blockIdx.x % 49;
    const int half = threadIdx.x >> 6;   // which 128-channel half (== wave id)
    const int p    = threadIdx.x & 63;   // pixel within tile (== lane)
    const int hw   = tile * 64 + p;      // 0..3135
    const int h    = hw / W_;
    const int w    = hw - h * W_;
    const float* xb = x + (size_t)b * C_ * HW_;

    // ---------- phase 1: partial r over this wave's 128 channels ----------
    float racc[64];
    #pragma unroll
    for (int i = 0; i < 64; ++i) racc[i] = 0.f;

    const int c0 = half * 128;
    for (int c8 = 0; c8 < 128; c8 += 8) {
        // 8 independent global loads in flight before any use (hide ~900cy HBM)
        float xv[8];
        #pragma unroll
        for (int u = 0; u < 8; ++u)
            xv[u] = xb[(size_t)(c0 + c8 + u) * HW_ + hw];
        #pragma unroll
        for (int u = 0; u < 8; ++u) {
            const float* wt = wredT + (size_t)(c0 + c8 + u) * 64;  // uniform -> s_load
            #pragma unroll
            for (int rr = 0; rr < 64; ++rr)
                racc[rr] += wt[rr] * xv[u];
        }
    }

    #pragma unroll
    for (int rr = 0; rr < 64; ++rr) r_lds[half][rr][p] = racc[rr];
    __syncthreads();

    // ---------- combine halves ----------
    float r[64];
    #pragma unroll
    for (int rr = 0; rr < 64; ++rr)
        r[rr] = r_lds[0][rr][p] + r_lds[1][rr][p];

    // ---------- per-group: span (9 kernel weights) + 9-tap involution ----------
    const bool hok0 = (h > 0), hok2 = (h < H_ - 1);
    const bool wok0 = (w > 0), wok2 = (w < W_ - 1);

    for (int gi = 0; gi < 8; ++gi) {
        const int g = half * 8 + gi;     // wave 0: groups 0-7, wave 1: groups 8-15
        float ker9[9];
        #pragma unroll
        for (int k = 0; k < 9; ++k) {
            const int kk = g * 9 + k;
            const float* sw = span_w + (size_t)kk * 64;   // uniform row -> s_load
            float a0 = span_b[kk], a1 = 0.f, a2 = 0.f, a3 = 0.f;
            #pragma unroll
            for (int rr = 0; rr < 64; rr += 4) {          // 4 chains: break dep latency
                a0 += sw[rr + 0] * r[rr + 0];
                a1 += sw[rr + 1] * r[rr + 1];
                a2 += sw[rr + 2] * r[rr + 2];
                a3 += sw[rr + 3] * r[rr + 3];
            }
            ker9[k] = (a0 + a1) + (a2 + a3);
        }
        #pragma unroll 1
        for (int cg = 0; cg < 16; ++cg) {
            const int c = g * 16 + cg;
            const float* xc = xb + (size_t)c * HW_;
            float acc = 0.f;
            #pragma unroll
            for (int k = 0; k < 9; ++k) {
                const int di = k / 3 - 1;
                const int dj = k % 3 - 1;
                const bool ok = (di < 0 ? hok0 : (di > 0 ? hok2 : true))
                             && (dj < 0 ? wok0 : (dj > 0 ? wok2 : true));
                if (ok) acc += ker9[k] * xc[hw + di * W_ + dj];
            }
            out[((size_t)b * C_ + c) * HW_ + hw] = acc;
        }
    }
}

extern "C" void kernel_launch(void* const* d_in, const int* in_sizes, int n_in,
                              void* d_out, int out_size, void* d_ws, size_t ws_size,
                              hipStream_t stream) {
    const float* x  = (const float*)d_in[0];
    const float* rw = (const float*)d_in[1];  // [64][256]
    const float* sw = (const float*)d_in[2];  // [144][64]
    const float* sb = (const float*)d_in[3];  // [144]
    float* out = (float*)d_out;
    float* rwT = (float*)d_ws;                // 256*64*4 = 64 KiB scratch

    transpose_rw<<<64, 256, 0, stream>>>(rw, rwT);
    inv_fused<<<16 * 49, 128, 0, stream>>>(x, rwT, sw, sb, out);
}

// Round 3
// 328.928 us; speedup vs baseline: 1.4896x; 1.4896x over previous
//
#include <hip/hip_runtime.h>

#define C_   256
#define CR_  64
#define HW_  3136
#define W_   56
#define H_   56
#define NK_  144   // K*K*G

// span_w [144][64] -> swT [64][144]  (36 864 B in d_ws -- within proven 64 KiB budget)
__global__ __launch_bounds__(256)
void transpose_sw(const float* __restrict__ sw, float* __restrict__ swT) {
    int idx = blockIdx.x * 256 + threadIdx.x;   // 9216 total
    int k  = idx / CR_;
    int rr = idx - k * CR_;
    swT[rr * NK_ + k] = sw[idx];
}

// One block = 64 pixels, 8 waves. Phase A: wave (rr-quarter, c-half) computes
// 16 partial r-rows over 128 channels. Phase B: wave wv computes ker rows
// [wv*18, wv*18+18) at its lane's pixel. Phase C: 9-tap involution, 32 chans/wave.
__global__ __launch_bounds__(512, 4)
void inv_fused(const float* __restrict__ x, const float* __restrict__ rw,
               const float* __restrict__ swT, const float* __restrict__ span_b,
               float* __restrict__ out) {
    __shared__ float rpart[2][CR_][64];   // [c-half][rr][pixel], 32 KiB, conflict-free

    const int b    = blockIdx.x / 49;
    const int tile = blockIdx.x % 49;
    const int wv   = threadIdx.x >> 6;
    const int lane = threadIdx.x & 63;
    const int hw   = tile * 64 + lane;
    const int h    = hw / W_;
    const int w    = hw - h * W_;
    const float* xb = x + (size_t)b * C_ * HW_;

    // Wave-uniform SGPR values -> weight reads ride the scalar pipe.
    const int rr0 = __builtin_amdgcn_readfirstlane((wv >> 1) * 16);
    const int c0  = __builtin_amdgcn_readfirstlane((wv & 1) * 128);
    const int ch  = wv & 1;

    // ---------- phase A: partial r (16 rr-rows over 128 channels) ----------
    float racc[16];
    #pragma unroll
    for (int j = 0; j < 16; ++j) racc[j] = 0.f;

    for (int i = 0; i < 128; i += 8) {
        float xv[8];                                   // 8 loads in flight
        #pragma unroll
        for (int u = 0; u < 8; ++u)
            xv[u] = xb[(size_t)(c0 + i + u) * HW_ + hw];   // coalesced 256B/wave
        #pragma unroll
        for (int j = 0; j < 16; ++j) {
            const float* wr = rw + (size_t)(rr0 + j) * C_ + c0 + i;  // uniform -> s_load_dwordx8
            #pragma unroll
            for (int u = 0; u < 8; ++u)
                racc[j] += wr[u] * xv[u];              // v_fmac, SGPR weight operand
        }
    }
    #pragma unroll
    for (int j = 0; j < 16; ++j)
        rpart[ch][rr0 + j][lane] = racc[j];
    __syncthreads();

    // ---------- combine halves into registers ----------
    float r[CR_];
    #pragma unroll 8
    for (int rr = 0; rr < CR_; ++rr)
        r[rr] = rpart[0][rr][lane] + rpart[1][rr][lane];

    // ---------- phase B: ker[k0..k0+17] = span_wT . r + b ----------
    const int k0 = __builtin_amdgcn_readfirstlane(wv * 18);
    float acc[18];
    #pragma unroll
    for (int k = 0; k < 18; ++k) acc[k] = span_b[k0 + k];

    #pragma unroll 4
    for (int rr = 0; rr < CR_; ++rr) {
        const float* wr = swT + (size_t)rr * NK_ + k0;   // uniform, 18 consecutive dwords
        #pragma unroll
        for (int k = 0; k < 18; ++k)
            acc[k] += wr[k] * r[rr];                     // 18 independent chains
    }

    // ---------- phase C: 9-tap involution for 32 channels ----------
    const bool hok0 = (h > 0), hok2 = (h < H_ - 1);
    const bool wok0 = (w > 0), wok2 = (w < W_ - 1);

    #pragma unroll
    for (int gi = 0; gi < 2; ++gi) {
        #pragma unroll 4
        for (int cg = 0; cg < 16; ++cg) {
            const int c = (wv * 2 + gi) * 16 + cg;
            const float* xc = xb + (size_t)c * HW_ + hw;
            float a = 0.f;
            #pragma unroll
            for (int k = 0; k < 9; ++k) {
                const int di = k / 3 - 1, dj = k % 3 - 1;
                const bool ok = (di < 0 ? hok0 : (di > 0 ? hok2 : true))
                             && (dj < 0 ? wok0 : (dj > 0 ? wok2 : true));
                if (ok) a += acc[gi * 9 + k] * xc[di * W_ + dj];
            }
            out[((size_t)b * C_ + c) * HW_ + hw] = a;    // coalesced store
        }
    }
}

extern "C" void kernel_launch(void* const* d_in, const int* in_sizes, int n_in,
                              void* d_out, int out_size, void* d_ws, size_t ws_size,
                              hipStream_t stream) {
    const float* x  = (const float*)d_in[0];
    const float* rw = (const float*)d_in[1];  // [64][256]
    const float* sw = (const float*)d_in[2];  // [144][64]
    const float* sb = (const float*)d_in[3];  // [144]
    float* out = (float*)d_out;
    float* swT = (float*)d_ws;                // 64*144*4 = 36 864 B

    transpose_sw<<<36, 256, 0, stream>>>(sw, swT);
    inv_fused<<<16 * 49, 512, 0, stream>>>(x, rw, swT, sb, out);
}